// Round 10
// baseline (18719.991 us; speedup 1.0000x reference)
//
#include <hip/hip_runtime.h>
#include <stdint.h>

// Problem: D-FPS. points_xyz (16, 131072, 3) fp32 -> indices (16, 4096) int32.
//
// Round 10 = round 8 (best: 9603 us; all-relaxed single-word protocol)
// with ONE structural change: ALL 16 waves poll the global slots directly
// (relaxed), eliminating the bc-fanout hop + follower discovery latency.
// r8 proved the r5/r6 all-wave-poll disasters were caused by acquire/release
// cache maintenance (buffer_inv / L2 writeback storms), not reader count —
// relaxed polls carry no maintenance ops. r9's micro-opts (coord prefetch,
// s_sleep, pipelined poll) all regressed and are reverted.
//
// Carried lessons: relaxed-only agent atomics; points in LDS SoA (allocator
// refuses register residency); FMA-chain distance (bit-exact vs reference);
// tag+payload in one 64-bit word; ring-2 parity slots (deadlock audit: a
// wave posts red[it+1] only after its own it-discovery, gs[it+1] waits on
// all reds, any it+2 overwrite waits on it+1 discovery -> no lost tags).

#define BATCH 16
#define NPTS  131072
#define NSAMP 4096
#define NBLK  16                  // blocks per batch
#define TPB   1024                // 16 waves
#define CHUNK (NPTS / NBLK)       // 8192 points per block
#define PPT   (CHUNK / TPB)       // 8 points per thread
#define NWAVE (TPB / 64)

typedef unsigned long long u64;
typedef unsigned int u32;

// Global slot word (8B, one per block per parity):
//   [63:32] dist bits (>=0 -> monotone) | [31:15] idx (17b) | [14:0] iter tag
// Poison 0xAA.. -> tag 0x2AAA; zero-init -> tag 0; live tags are 1..4095.

__global__ void fps_init_kernel(u64* __restrict__ ws) {
    int i = blockIdx.x * blockDim.x + threadIdx.x;
    if (i < BATCH * 2 * NBLK) ws[i] = 0ull;
}

__global__ __launch_bounds__(TPB, 4) void fps_kernel(
        const float* __restrict__ xyz, int* __restrict__ out,
        u64* __restrict__ gslot) {
    const int blk   = blockIdx.x;
    const int b     = blk & 15;    // batch: a batch's 16 blocks have constant
    const int chunk = blk >> 4;    // blk%8 -> same-XCD heuristic
    const int tid   = threadIdx.x;
    const int w     = tid >> 6;
    const int lane  = tid & 63;

    const float* bxyz = xyz + (size_t)b * NPTS * 3;
    const int base = chunk * CHUNK;

    // ---- LDS: SoA points + red words ----
    __shared__ float2 sxy[CHUNK];          // 64 KB
    __shared__ float  szz[CHUNK];          // 32 KB
    __shared__ u64 red[2][NWAVE];          // 256 B
    for (int i = tid; i < CHUNK; i += TPB) {
        size_t p = (size_t)(base + i) * 3;
        sxy[i] = make_float2(bxyz[p + 0], bxyz[p + 1]);
        szz[i] = bxyz[p + 2];
    }
    if (tid < 2 * NWAVE) ((u64*)red)[tid] = ~0ull;  // tag 0x7FFF: invalid
    if (tid == 0 && chunk == 0) out[b * NSAMP] = 0; // iter 0 emits index 0
    __syncthreads();   // staging visibility (only block-wide barrier)

    float pd[PPT];
#pragma unroll
    for (int k = 0; k < PPT; ++k) pd[k] = __builtin_inff();

    float cx = bxyz[0], cy = bxyz[1], cz = bxyz[2];

    u64* gs = gslot + (size_t)b * 2 * NBLK;   // [2][NBLK]

    for (int it = 1; it < NSAMP; ++it) {
        const int par = it & 1;
        u64* gsp = gs + par * NBLK;

        // ---- update min-dists + local argmax (LDS + registers) ----
        // Verified arithmetic (round 2, absmax 0): FMA-contracted
        //   d = fma(dz,dz, fma(dy,dy, dx*dx)), subs exact-rounded.
        float bd = -1.0f;
        int   bk = 0;
#pragma unroll
        for (int k = 0; k < PPT; ++k) {
            int i = tid + TPB * k;
            float2 xy = sxy[i];
            float  z  = szz[i];
            float dx = __fsub_rn(xy.x, cx);
            float dy = __fsub_rn(xy.y, cy);
            float dz = __fsub_rn(z,    cz);
            float d  = __builtin_fmaf(dz, dz,
                         __builtin_fmaf(dy, dy, __fmul_rn(dx, dx)));
            float nd = fminf(pd[k], d);
            pd[k] = nd;
            // strict >: earliest k wins (gi ascends with k) = first-occurrence
            if (nd > bd) { bd = nd; bk = k; }
        }
        u32 gi = (u32)(base + tid + TPB * bk);
        u64 key = ((u64)__float_as_uint(bd) << 32) | (u64)(~gi);

        // ---- wave butterfly (max dist, then min index) ----
#pragma unroll
        for (int off = 1; off <= 32; off <<= 1) {
            u64 o = __shfl_xor(key, off, 64);
            key = key > o ? key : o;
        }
        if (lane == 0) {
            u32 db  = (u32)(key >> 32);
            u32 idx = ~(u32)key;          // = gi (fits 17 bits)
            __hip_atomic_store(&red[par][w],
                               ((u64)db << 32) | ((u64)idx << 15) | (u64)it,
                               __ATOMIC_RELAXED, __HIP_MEMORY_SCOPE_WORKGROUP);
        }

        if (w == 0) {
            // ---- wave0: combine the 16 wave entries, publish block winner ----
            u64 v; bool ok;
            do {
                v  = (lane < NWAVE)
                       ? __hip_atomic_load(&red[par][lane], __ATOMIC_RELAXED,
                                           __HIP_MEMORY_SCOPE_WORKGROUP)
                       : 0ull;
                ok = (lane < NWAVE) ? ((v & 0x7FFFull) == (u64)it) : true;
            } while (__ballot(ok) != ~0ull);
            u64 k2 = 0ull;
            if (lane < NWAVE) {
                u32 db  = (u32)(v >> 32);
                u32 idx = (u32)((v >> 15) & 0x1FFFFu);
                k2 = ((u64)db << 32) | (u64)(~idx);
            }
#pragma unroll
            for (int off = 1; off <= 8; off <<= 1) {
                u64 o = __shfl_xor(k2, off, 64);
                k2 = k2 > o ? k2 : o;
            }
            if (lane == 0) {
                u32 db  = (u32)(k2 >> 32);
                u32 idx = ~(u32)k2;
                __hip_atomic_store(&gsp[chunk],
                                   ((u64)db << 32) | ((u64)idx << 15) | (u64)it,
                                   __ATOMIC_RELAXED, __HIP_MEMORY_SCOPE_AGENT);
            }
        }

        // ---- ALL waves: relaxed-poll the 16 slot words directly ----
        // (no fanout hop; relaxed loads carry no cache-maintenance ops)
        u64 v; bool ok;
        do {
            v  = (lane < NBLK)
                   ? __hip_atomic_load(&gsp[lane], __ATOMIC_RELAXED,
                                       __HIP_MEMORY_SCOPE_AGENT)
                   : 0ull;
            ok = (lane < NBLK) ? ((v & 0x7FFFull) == (u64)it) : true;
        } while (__ballot(ok) != ~0ull);
        u64 k3 = 0ull;
        if (lane < NBLK) {
            u32 db  = (u32)(v >> 32);
            u32 idx = (u32)((v >> 15) & 0x1FFFFu);
            k3 = ((u64)db << 32) | (u64)(~idx);
        }
#pragma unroll
        for (int off = 1; off <= 32; off <<= 1) {  // winner key on ALL 64 lanes
            u64 o = __shfl_xor(k3, off, 64);
            k3 = k3 > o ? k3 : o;
        }
        u32 widx = ~(u32)k3;
        if (w == 0 && lane == 0 && chunk == 0) out[b * NSAMP + it] = (int)widx;
        // winner coords: same-address broadcast load (L1 after first wave)
        cx = bxyz[3 * (size_t)widx + 0];
        cy = bxyz[3 * (size_t)widx + 1];
        cz = bxyz[3 * (size_t)widx + 2];
    }
}

extern "C" void kernel_launch(void* const* d_in, const int* in_sizes, int n_in,
                              void* d_out, int out_size, void* d_ws, size_t ws_size,
                              hipStream_t stream) {
    const float* xyz = (const float*)d_in[0];
    int* out = (int*)d_out;
    u64* gslot = (u64*)d_ws;   // [BATCH][2][NBLK] u64 = 4 KB

    hipLaunchKernelGGL(fps_init_kernel, dim3(1), dim3(512), 0, stream, gslot);
    hipLaunchKernelGGL(fps_kernel, dim3(BATCH * NBLK), dim3(TPB), 0, stream,
                       xyz, out, gslot);
}

// Round 11
// 13578.806 us; speedup vs baseline: 1.3786x; 1.3786x over previous
//
#include <hip/hip_runtime.h>
#include <stdint.h>

// Problem: D-FPS. points_xyz (16, 131072, 3) fp32 -> indices (16, 4096) int32.
//
// Round 11 = round 8 (best: 9603 us) + two audited serialized-cycle cuts:
//  (1) last-arrival publish: waves combine via ds_max_u64 + release-scope LDS
//      arrival counter; the 16th wave reads/resets and issues the agent store
//      (removes w0's red tag-poll + shuffle combine from the chain).
//  (2) double-sampled gs poll: two independent loads per spin round halve the
//      sampling period of the discovery loop.
// Locked-in lessons (r2-r10):
//  - relaxed-only AGENT atomics; tag+payload in one 64-bit word (acquire/
//    release at agent scope = chip-wide cache-maintenance storms, r7).
//  - ONE relaxed polling wave per block (256 pollers ok, 4096 = 2x slower, r10).
//  - points in LDS SoA (the allocator never keeps them register-resident).
//  - FMA-chain distance d = fma(dz,dz, fma(dy,dy, dx*dx)), subs exact-rounded
//    (bit-exact vs reference trajectory, r2).
//  - workgroup-scope acq/rel on LDS is lgkmcnt-only (cheap, no cache ops).

#define BATCH 16
#define NPTS  131072
#define NSAMP 4096
#define NBLK  16                  // blocks per batch
#define TPB   1024                // 16 waves
#define CHUNK (NPTS / NBLK)       // 8192 points per block
#define PPT   (CHUNK / TPB)       // 8 points per thread
#define NWAVE (TPB / 64)

typedef unsigned long long u64;
typedef unsigned int u32;

// Global slot word (8B, one per block per parity):
//   [63:32] dist bits (>=0 -> monotone) | [31:15] idx (17b) | [14:0] iter tag
// Poison 0xAA.. -> tag 0x2AAA; zero-init -> tag 0; live tags are 1..4095.
// Ring-2 by parity; ordering via the value-dependence chain (r8-proven).
//
// LDS combine words (per parity): mx = running max of (dist<<32 | ~gi)
// (identity 0: every real key > 0 since ~gi != 0), cn = arrival counter.
// The trigger wave (old count == NWAVE-1) reads mx, resets both, publishes.
// Reset-safety: trigger is the SOLE reader of mx/cn; reset precedes this
// block's gs[it] store, which precedes bc[it], which precedes any wave's
// iter-(it+1) work, which precedes any parity reuse at it+2.

__global__ void fps_init_kernel(u64* __restrict__ ws) {
    int i = blockIdx.x * blockDim.x + threadIdx.x;
    if (i < BATCH * 2 * NBLK) ws[i] = 0ull;
}

__global__ __launch_bounds__(TPB, 4) void fps_kernel(
        const float* __restrict__ xyz, int* __restrict__ out,
        u64* __restrict__ gslot) {
    const int blk   = blockIdx.x;
    const int b     = blk & 15;    // batch: a batch's 16 blocks have constant
    const int chunk = blk >> 4;    // blk%8 -> same-XCD heuristic
    const int tid   = threadIdx.x;
    const int w     = tid >> 6;
    const int lane  = tid & 63;

    const float* bxyz = xyz + (size_t)b * NPTS * 3;
    const int base = chunk * CHUNK;

    // ---- LDS: SoA points + combine words + broadcast ----
    __shared__ float2 sxy[CHUNK];          // 64 KB
    __shared__ float  szz[CHUNK];          // 32 KB
    __shared__ u64 mx[2];                  // per-parity running max
    __shared__ u32 cn[2];                  // per-parity arrival counter
    __shared__ u64 bc[2];                  // broadcast: widx<<32 | it
    for (int i = tid; i < CHUNK; i += TPB) {
        size_t p = (size_t)(base + i) * 3;
        sxy[i] = make_float2(bxyz[p + 0], bxyz[p + 1]);
        szz[i] = bxyz[p + 2];
    }
    if (tid < 2) { mx[tid] = 0ull; cn[tid] = 0u; bc[tid] = ~0ull; }
    if (tid == 0 && chunk == 0) out[b * NSAMP] = 0; // iter 0 emits index 0
    __syncthreads();   // staging visibility (only block-wide barrier)

    float pd[PPT];
#pragma unroll
    for (int k = 0; k < PPT; ++k) pd[k] = __builtin_inff();

    float cx = bxyz[0], cy = bxyz[1], cz = bxyz[2];

    u64* gs = gslot + (size_t)b * 2 * NBLK;   // [2][NBLK]

    for (int it = 1; it < NSAMP; ++it) {
        const int par = it & 1;
        u64* gsp = gs + par * NBLK;

        // ---- update min-dists + local argmax (LDS + registers) ----
        // Verified arithmetic (round 2, absmax 0): FMA-contracted
        //   d = fma(dz,dz, fma(dy,dy, dx*dx)), subs exact-rounded.
        float bd = -1.0f;
        int   bk = 0;
#pragma unroll
        for (int k = 0; k < PPT; ++k) {
            int i = tid + TPB * k;
            float2 xy = sxy[i];
            float  z  = szz[i];
            float dx = __fsub_rn(xy.x, cx);
            float dy = __fsub_rn(xy.y, cy);
            float dz = __fsub_rn(z,    cz);
            float d  = __builtin_fmaf(dz, dz,
                         __builtin_fmaf(dy, dy, __fmul_rn(dx, dx)));
            float nd = fminf(pd[k], d);
            pd[k] = nd;
            // strict >: earliest k wins (gi ascends with k) = first-occurrence
            if (nd > bd) { bd = nd; bk = k; }
        }
        u32 gi = (u32)(base + tid + TPB * bk);
        u64 key = ((u64)__float_as_uint(bd) << 32) | (u64)(~gi);

        // ---- wave butterfly (max dist, then min index) ----
#pragma unroll
        for (int off = 1; off <= 32; off <<= 1) {
            u64 o = __shfl_xor(key, off, 64);
            key = key > o ? key : o;
        }

        // ---- last-arrival combine: ds_max + release counter ----
        bool trigger = false;
        if (lane == 0) {
            __hip_atomic_fetch_max(&mx[par], key, __ATOMIC_RELAXED,
                                   __HIP_MEMORY_SCOPE_WORKGROUP);
            // RELEASE orders the max before the count (lgkmcnt only);
            // ACQUIRE half lets the trigger read mx coherently.
            u32 old = __hip_atomic_fetch_add(&cn[par], 1u, __ATOMIC_ACQ_REL,
                                             __HIP_MEMORY_SCOPE_WORKGROUP);
            trigger = (old == NWAVE - 1);
            if (trigger) {
                u64 m = __hip_atomic_load(&mx[par], __ATOMIC_RELAXED,
                                          __HIP_MEMORY_SCOPE_WORKGROUP);
                // reset for reuse at it+2 (sole reader; see header audit)
                __hip_atomic_store(&mx[par], 0ull, __ATOMIC_RELAXED,
                                   __HIP_MEMORY_SCOPE_WORKGROUP);
                __hip_atomic_store(&cn[par], 0u, __ATOMIC_RELAXED,
                                   __HIP_MEMORY_SCOPE_WORKGROUP);
                u32 db  = (u32)(m >> 32);
                u32 idx = ~(u32)m;          // = gi (fits 17 bits)
                __hip_atomic_store(&gsp[chunk],
                                   ((u64)db << 32) | ((u64)idx << 15) | (u64)it,
                                   __ATOMIC_RELAXED, __HIP_MEMORY_SCOPE_AGENT);
            }
        }

        if (w == 0) {
            // ---- wave0: double-sampled relaxed poll of the 16 slot words ----
            u64 v; bool ok;
            for (;;) {
                u64 v1 = (lane < NBLK)
                           ? __hip_atomic_load(&gsp[lane], __ATOMIC_RELAXED,
                                               __HIP_MEMORY_SCOPE_AGENT)
                           : 0ull;
                u64 v2 = (lane < NBLK)
                           ? __hip_atomic_load(&gsp[lane], __ATOMIC_RELAXED,
                                               __HIP_MEMORY_SCOPE_AGENT)
                           : 0ull;
                ok = (lane < NBLK) ? ((v1 & 0x7FFFull) == (u64)it) : true;
                if (__ballot(ok) == ~0ull) { v = v1; break; }
                ok = (lane < NBLK) ? ((v2 & 0x7FFFull) == (u64)it) : true;
                if (__ballot(ok) == ~0ull) { v = v2; break; }
            }
            u64 k3 = 0ull;
            if (lane < NBLK) {
                u32 db  = (u32)(v >> 32);
                u32 idx = (u32)((v >> 15) & 0x1FFFFu);
                k3 = ((u64)db << 32) | (u64)(~idx);
            }
#pragma unroll
            for (int off = 1; off <= 32; off <<= 1) {  // winner on ALL 64 lanes
                u64 o = __shfl_xor(k3, off, 64);
                k3 = k3 > o ? k3 : o;
            }
            u32 widx = ~(u32)k3;
            if (lane == 0) {
                if (chunk == 0) out[b * NSAMP + it] = (int)widx;
                __hip_atomic_store(&bc[par],
                                   ((u64)widx << 32) | (u64)(u32)it,
                                   __ATOMIC_RELAXED, __HIP_MEMORY_SCOPE_WORKGROUP);
            }
            // coords: same-address broadcast load (L1/L2)
            cx = bxyz[3 * (size_t)widx + 0];
            cy = bxyz[3 * (size_t)widx + 1];
            cz = bxyz[3 * (size_t)widx + 2];
        } else {
            // ---- other waves: wait for tagged LDS broadcast ----
            u64 bv;
            do {
                bv = __hip_atomic_load(&bc[par], __ATOMIC_RELAXED,
                                       __HIP_MEMORY_SCOPE_WORKGROUP);
            } while ((u32)bv != (u32)it);
            u32 widx = (u32)(bv >> 32);
            cx = bxyz[3 * (size_t)widx + 0];
            cy = bxyz[3 * (size_t)widx + 1];
            cz = bxyz[3 * (size_t)widx + 2];
        }
    }
}

extern "C" void kernel_launch(void* const* d_in, const int* in_sizes, int n_in,
                              void* d_out, int out_size, void* d_ws, size_t ws_size,
                              hipStream_t stream) {
    const float* xyz = (const float*)d_in[0];
    int* out = (int*)d_out;
    u64* gslot = (u64*)d_ws;   // [BATCH][2][NBLK] u64 = 4 KB

    hipLaunchKernelGGL(fps_init_kernel, dim3(1), dim3(512), 0, stream, gslot);
    hipLaunchKernelGGL(fps_kernel, dim3(BATCH * NBLK), dim3(TPB), 0, stream,
                       xyz, out, gslot);
}